// Round 4
// baseline (411.831 us; speedup 1.0000x reference)
//
#include <hip/hip_runtime.h>
#include <math.h>

#define B_ 4
#define C_ 512
#define D_ 128
#define N_ 4096

typedef short s4v __attribute__((ext_vector_type(4)));
typedef short s8v __attribute__((ext_vector_type(8)));
typedef float f4v __attribute__((ext_vector_type(4)));

__device__ __forceinline__ unsigned short f2bf(float x) {
    union { float f; unsigned u; } v; v.f = x;
    unsigned r = v.u + 0x7FFF + ((v.u >> 16) & 1);   // RNE
    return (unsigned short)(r >> 16);
}
__device__ __forceinline__ float bf2f(unsigned short h) {
    union { unsigned u; float f; } v; v.u = ((unsigned)h) << 16; return v.f;
}

// ---------------------------------------------------------------------------
// W/bias pre-convert: Wb rows [0:64]=Wq | [64:128]=Wk | [128:640]=Wv |
// [640:704]=Wdq | [704:768]=Wdk (bf16, row-major 512). biasb same order f32.
// ---------------------------------------------------------------------------
__global__ __launch_bounds__(256) void cvt_w_kernel(
    const float* __restrict__ Wq,  const float* __restrict__ bq,
    const float* __restrict__ Wk,  const float* __restrict__ bk,
    const float* __restrict__ Wdq, const float* __restrict__ bdq,
    const float* __restrict__ Wdk, const float* __restrict__ bdk,
    const float* __restrict__ Wv,  const float* __restrict__ bv,
    unsigned short* __restrict__ Wb, float* __restrict__ biasb)
{
    int t = blockIdx.x * 256 + threadIdx.x;        // 192 blocks
    int e0 = t * 8;
    int row = e0 >> 9, c = e0 & 511;
    const float* src; int r0;
    if (row < 64)       { src = Wq;  r0 = row; }
    else if (row < 128) { src = Wk;  r0 = row - 64; }
    else if (row < 640) { src = Wv;  r0 = row - 128; }
    else if (row < 704) { src = Wdq; r0 = row - 640; }
    else                { src = Wdk; r0 = row - 704; }
    const float* p = src + (size_t)r0 * 512 + c;
    s8v o;
    #pragma unroll
    for (int u = 0; u < 8; ++u) ((unsigned short*)&o)[u] = f2bf(p[u]);
    *(s8v*)&Wb[e0] = o;
    if (blockIdx.x == 0) {
        #pragma unroll
        for (int s = 0; s < 3; ++s) {
            int o2 = threadIdx.x + 256 * s;
            float v;
            if (o2 < 64)       v = bq[o2];
            else if (o2 < 128) v = bk[o2 - 64];
            else if (o2 < 640) v = bv[o2 - 128];
            else if (o2 < 704) v = bdq[o2 - 640];
            else               v = bdk[o2 - 704];
            biasb[o2] = v;
        }
    }
}

// ---------------------------------------------------------------------------
// Projection GEMM, x read ONCE. Grid (128 i-tiles of 32, 4 b, 2 streams).
// Block stages its x slice [32 i x 512 c] -> LDS bf16 (transposed), then
// loops o-chunks of 32 (rgb: 20 chunks = Wq|Wk|Wv; dep: 4 = Wdq|Wdk).
// W A-frags read directly from global bf16 (L1/L2-hot, shared by all blocks).
// Wave w: o-16 half = w&1, i-16 half = w>>1. V-chunks swap MFMA operands
// (A=x,B=W) so lane holds 4 consecutive j at fixed c -> b64 stores in [c,j].
// LDS 33.3 KB -> 4 blocks/CU.
// ---------------------------------------------------------------------------
__global__ __launch_bounds__(256) void proj_kernel(
    const float* __restrict__ x_rgb, const float* __restrict__ x_dep,
    const unsigned short* __restrict__ Wb, const float* __restrict__ biasb,
    unsigned short* __restrict__ Q, unsigned short* __restrict__ K,
    unsigned short* __restrict__ V)
{
    __shared__ __align__(16) unsigned short Xs[32 * 520];
    const int i0 = blockIdx.x * 32;
    const int b  = blockIdx.y;
    const int st = blockIdx.z;                    // 0=rgb, 1=dep
    const int t = threadIdx.x, w = t >> 6;
    const int lane = t & 63, col = lane & 15, quad = lane >> 4;

    const float* Xb = (st ? x_dep : x_rgb) + (size_t)b * C_ * N_;

    // stage x [512 c x 32 i] -> Xs[i][c] bf16 (4x4 transpose blocks)
    #pragma unroll
    for (int s = 0; s < 4; ++s) {
        int p  = t + 256 * s;
        int ig = p & 7, cq = p >> 3;              // ig: i-granule, cq: c-granule
        int i  = ig * 4, c = cq * 4;
        const float* xp = Xb + (size_t)c * N_ + i0 + i;
        float4 r0 = *(const float4*)(xp);
        float4 r1 = *(const float4*)(xp + N_);
        float4 r2 = *(const float4*)(xp + 2 * N_);
        float4 r3 = *(const float4*)(xp + 3 * N_);
        s4v p0 = { (short)f2bf(r0.x), (short)f2bf(r1.x), (short)f2bf(r2.x), (short)f2bf(r3.x) };
        s4v p1 = { (short)f2bf(r0.y), (short)f2bf(r1.y), (short)f2bf(r2.y), (short)f2bf(r3.y) };
        s4v p2 = { (short)f2bf(r0.z), (short)f2bf(r1.z), (short)f2bf(r2.z), (short)f2bf(r3.z) };
        s4v p3 = { (short)f2bf(r0.w), (short)f2bf(r1.w), (short)f2bf(r2.w), (short)f2bf(r3.w) };
        *(s4v*)&Xs[(i + 0) * 520 + c] = p0;
        *(s4v*)&Xs[(i + 1) * 520 + c] = p1;
        *(s4v*)&Xs[(i + 2) * 520 + c] = p2;
        *(s4v*)&Xs[(i + 3) * 520 + c] = p3;
    }
    __syncthreads();

    const int nmc   = st ? 4 : 20;
    const int obase = st ? 640 : 0;
    const int ot = (w & 1) * 16, it = (w >> 1) * 16;

    for (int mc = 0; mc < nmc; ++mc) {
        const int o0 = obase + mc * 32 + ot;
        const unsigned short* wp = Wb + ((size_t)(o0 + col) << 9) + quad * 8;
        const unsigned short* xp = &Xs[(it + col) * 520 + quad * 8];
        f4v acc = {0.f, 0.f, 0.f, 0.f};
        const bool isV = (st == 0) && (mc >= 4);
        if (!isV) {
            #pragma unroll 4
            for (int kk = 0; kk < 16; ++kk) {
                s8v wf = *(const s8v*)(wp + kk * 32);
                s8v xf = *(const s8v*)(xp + kk * 32);
                acc = __builtin_amdgcn_mfma_f32_16x16x32_bf16(wf, xf, acc, 0, 0, 0);
            }
            // lane: o = o0 + quad*4 + r, i = i0 + it + col
            float4 bi = *(const float4*)&biasb[o0 + quad * 4];
            s4v pk = { (short)f2bf(acc[0] + bi.x), (short)f2bf(acc[1] + bi.y),
                       (short)f2bf(acc[2] + bi.z), (short)f2bf(acc[3] + bi.w) };
            unsigned short* dst; int dbase;
            if (o0 < 64)        { dst = Q; dbase = o0; }
            else if (o0 < 128)  { dst = K; dbase = o0 - 64; }
            else if (o0 < 704)  { dst = Q; dbase = 64 + (o0 - 640); }
            else                { dst = K; dbase = 64 + (o0 - 704); }
            *(s4v*)&dst[((size_t)b * N_ + i0 + it + col) * D_ + dbase + quad * 4] = pk;
        } else {
            #pragma unroll 4
            for (int kk = 0; kk < 16; ++kk) {
                s8v wf = *(const s8v*)(wp + kk * 32);
                s8v xf = *(const s8v*)(xp + kk * 32);
                acc = __builtin_amdgcn_mfma_f32_16x16x32_bf16(xf, wf, acc, 0, 0, 0);
            }
            // lane: c = o0-128+col, j = i0 + it + quad*4 + r
            float bi = biasb[o0 + col];
            s4v pk = { (short)f2bf(acc[0] + bi), (short)f2bf(acc[1] + bi),
                       (short)f2bf(acc[2] + bi), (short)f2bf(acc[3] + bi) };
            int c = o0 - 128 + col;
            *(s4v*)&V[((size_t)b * C_ + c) * N_ + i0 + it + quad * 4] = pk;
        }
    }
}

// ---------------------------------------------------------------------------
// MFMA flash attention, j-split 2-way (unnormalized softmax -> partials are
// exactly additive). Grid (64 i-tiles, 4 b, 2 j-halves) = 512 blocks =
// 2/CU for barrier overlap. BM=64, BN=32, 64 iters/block.
// S^T per wave: (ih = i-32-half, jq = j-16-half) -> 2 tiles; K frag reads
// halved vs all-wave-reads-all-K. PV c-partitioned (wave owns 128 c).
// Outputs: O partial (bf16, [jh][b][c][i]) + l partial (f32, [jh][b][i]).
// LDS: Ks[32][136] 8704 | Ps[64][40] 5120 | Vs[512][40] 40960 | lred 512.
// ---------------------------------------------------------------------------
__global__ __launch_bounds__(256) void attn_kernel(
    const unsigned short* __restrict__ Q, const unsigned short* __restrict__ K,
    const unsigned short* __restrict__ V,
    unsigned short* __restrict__ O_ws, float* __restrict__ l_ws)
{
    __shared__ __align__(16) unsigned short Ks[32 * 136];
    __shared__ __align__(16) unsigned short Ps[64 * 40];
    __shared__ __align__(16) unsigned char  VOs[512 * 40 * 2];
    __shared__ float lred[2][64];
    unsigned short* Vs = (unsigned short*)VOs;
    float*          Os = (float*)VOs;

    const int b  = blockIdx.y;
    const int i0 = blockIdx.x * 64;
    const int jb = blockIdx.z * 2048;
    const int t = threadIdx.x, w = t >> 6;
    const int lane = t & 63, col = lane & 15, quad = lane >> 4;
    const int ih = w & 1, jq = w >> 1;

    const unsigned short* Kg = K + (size_t)b * N_ * D_;
    const unsigned short* Vg = V + (size_t)b * C_ * N_;

    // Q B-frags for this wave's 2 i-16 groups (rows ih*32 + ig*16 + col)
    s8v qf[2][4];
    #pragma unroll
    for (int ig = 0; ig < 2; ++ig) {
        const unsigned short* qr =
            Q + ((size_t)b * N_ + i0 + ih * 32 + ig * 16 + col) * D_ + quad * 8;
        #pragma unroll
        for (int kk = 0; kk < 4; ++kk) qf[ig][kk] = *(const s8v*)(qr + kk * 32);
    }

    f4v accO[4][8];
    #pragma unroll
    for (int rt = 0; rt < 4; ++rt)
        #pragma unroll
        for (int ct = 0; ct < 8; ++ct) accO[rt][ct] = (f4v){0.f, 0.f, 0.f, 0.f};
    float lsum[2] = {0.f, 0.f};

    s8v kreg[2], vreg[8];
    {   // prefetch tile 0
        #pragma unroll
        for (int s = 0; s < 2; ++s) {
            int gi = t + 256 * s;
            kreg[s] = *(const s8v*)&Kg[(size_t)(jb + (gi >> 4)) * D_ + (gi & 15) * 8];
        }
        #pragma unroll
        for (int s = 0; s < 8; ++s) {
            int gi = t + 256 * s;
            vreg[s] = *(const s8v*)&Vg[(size_t)(gi >> 2) * N_ + jb + (gi & 3) * 8];
        }
    }

    for (int tt = 0; tt < 64; ++tt) {
        // commit prefetched tile
        #pragma unroll
        for (int s = 0; s < 2; ++s) {
            int gi = t + 256 * s;
            *(s8v*)&Ks[(gi >> 4) * 136 + (gi & 15) * 8] = kreg[s];
        }
        #pragma unroll
        for (int s = 0; s < 8; ++s) {
            int gi = t + 256 * s;
            *(s8v*)&Vs[(gi >> 2) * 40 + (gi & 3) * 8] = vreg[s];
        }
        __syncthreads();
        if (tt + 1 < 64) {
            const int j1 = jb + (tt + 1) * 32;
            #pragma unroll
            for (int s = 0; s < 2; ++s) {
                int gi = t + 256 * s;
                kreg[s] = *(const s8v*)&Kg[(size_t)(j1 + (gi >> 4)) * D_ + (gi & 15) * 8];
            }
            #pragma unroll
            for (int s = 0; s < 8; ++s) {
                int gi = t + 256 * s;
                vreg[s] = *(const s8v*)&Vg[(size_t)(gi >> 2) * N_ + j1 + (gi & 3) * 8];
            }
        }
        // ---- S^T = K Q^T for this wave's (ih, jq): 2 tiles ----
        f4v s0 = (f4v){0.f, 0.f, 0.f, 0.f};
        f4v s1 = (f4v){0.f, 0.f, 0.f, 0.f};
        #pragma unroll
        for (int kk = 0; kk < 4; ++kk) {
            s8v kf = *(const s8v*)&Ks[(jq * 16 + col) * 136 + kk * 32 + quad * 8];
            s0 = __builtin_amdgcn_mfma_f32_16x16x32_bf16(kf, qf[0][kk], s0, 0, 0, 0);
            s1 = __builtin_amdgcn_mfma_f32_16x16x32_bf16(kf, qf[1][kk], s1, 0, 0, 0);
        }
        // ---- P = exp(S): lane holds i=col, j = jq*16 + quad*4 + r ----
        #pragma unroll
        for (int ig = 0; ig < 2; ++ig) {
            f4v sv = ig ? s1 : s0;
            s4v p; float ls = 0.f;
            #pragma unroll
            for (int r = 0; r < 4; ++r) {
                float e = __expf(sv[r]);
                ls += e;
                p[r] = (short)f2bf(e);
            }
            lsum[ig] += ls;
            *(s4v*)&Ps[(ih * 32 + ig * 16 + col) * 40 + jq * 16 + quad * 4] = p;
        }
        __syncthreads();
        // ---- O += P V : wave w owns c in [w*128, w*128+128) ----
        s8v pf[4];
        #pragma unroll
        for (int rt = 0; rt < 4; ++rt)
            pf[rt] = *(const s8v*)&Ps[(rt * 16 + col) * 40 + quad * 8];
        #pragma unroll
        for (int ct = 0; ct < 8; ++ct) {
            s8v vf = *(const s8v*)&Vs[(w * 128 + ct * 16 + col) * 40 + quad * 8];
            #pragma unroll
            for (int rt = 0; rt < 4; ++rt)
                accO[rt][ct] = __builtin_amdgcn_mfma_f32_16x16x32_bf16(pf[rt], vf, accO[rt][ct], 0, 0, 0);
        }
        __syncthreads();
    }

    // ---- partial l: reduce over quads, combine jq halves via LDS ----
    #pragma unroll
    for (int ig = 0; ig < 2; ++ig) {
        float v = lsum[ig];
        v += __shfl_xor(v, 16);
        v += __shfl_xor(v, 32);
        if (quad == 0) lred[jq][ih * 32 + ig * 16 + col] = v;
    }

    const size_t jzoff = ((size_t)blockIdx.z * B_ + b) * C_ * N_;

    // ---- epilogue: per-wave 128-c slice -> LDS transpose -> bf16 stores ----
    for (int h = 0; h < 4; ++h) {
        __syncthreads();
        if (w == h) {
            #pragma unroll
            for (int ct = 0; ct < 8; ++ct)
                #pragma unroll
                for (int rt = 0; rt < 4; ++rt)
                    *(f4v*)&Os[(ct * 16 + col) * 68 + rt * 16 + quad * 4] = accO[rt][ct];
        }
        __syncthreads();
        if (h == 0 && t < 64)
            l_ws[((size_t)blockIdx.z * B_ + b) * N_ + i0 + t] = lred[0][t] + lred[1][t];
        #pragma unroll
        for (int s = 0; s < 8; ++s) {
            int g2 = t + 256 * s;
            int c = g2 >> 4, io = (g2 & 15) * 4;
            float4 o4 = *(float4*)&Os[c * 68 + io];
            s4v pk = { (short)f2bf(o4.x), (short)f2bf(o4.y),
                       (short)f2bf(o4.z), (short)f2bf(o4.w) };
            *(s4v*)&O_ws[jzoff + (size_t)(h * 128 + c) * N_ + i0 + io] = pk;
        }
    }
}

// ---------------------------------------------------------------------------
// Combine: out = gamma * (O0+O1)/(l0+l1) + x_rgb
// ---------------------------------------------------------------------------
__global__ __launch_bounds__(256) void combine_kernel(
    const unsigned short* __restrict__ O_ws, const float* __restrict__ l_ws,
    const float* __restrict__ x_rgb, const float* __restrict__ gamma,
    float* __restrict__ out)
{
    const size_t half = (size_t)B_ * C_ * N_;
    int idx = blockIdx.x * 256 + threadIdx.x;     // 8192 blocks
    int i = (idx & 1023) * 4;
    int c = (idx >> 10) & 511;
    int b = idx >> 19;
    size_t base = ((size_t)b * C_ + c) * N_ + i;
    s4v o0 = *(const s4v*)&O_ws[base];
    s4v o1 = *(const s4v*)&O_ws[half + base];
    float4 l0 = *(const float4*)&l_ws[(size_t)b * N_ + i];
    float4 l1 = *(const float4*)&l_ws[(size_t)(B_ + b) * N_ + i];
    float4 x4 = *(const float4*)&x_rgb[base];
    float g = gamma[0];
    float4 r;
    r.x = g * (bf2f((unsigned short)o0[0]) + bf2f((unsigned short)o1[0])) / (l0.x + l1.x) + x4.x;
    r.y = g * (bf2f((unsigned short)o0[1]) + bf2f((unsigned short)o1[1])) / (l0.y + l1.y) + x4.y;
    r.z = g * (bf2f((unsigned short)o0[2]) + bf2f((unsigned short)o1[2])) / (l0.z + l1.z) + x4.z;
    r.w = g * (bf2f((unsigned short)o0[3]) + bf2f((unsigned short)o1[3])) / (l0.w + l1.w) + x4.w;
    *(float4*)&out[base] = r;
}

// ---------------------------------------------------------------------------
extern "C" void kernel_launch(void* const* d_in, const int* in_sizes, int n_in,
                              void* d_out, int out_size, void* d_ws, size_t ws_size,
                              hipStream_t stream) {
    (void)in_sizes; (void)n_in; (void)out_size; (void)ws_size;
    const float* x_rgb = (const float*)d_in[0];
    const float* x_dep = (const float*)d_in[1];
    const float* Wq    = (const float*)d_in[2];
    const float* bq    = (const float*)d_in[3];
    const float* Wk    = (const float*)d_in[4];
    const float* bk    = (const float*)d_in[5];
    const float* Wdq   = (const float*)d_in[6];
    const float* bdq   = (const float*)d_in[7];
    const float* Wdk   = (const float*)d_in[8];
    const float* bdk   = (const float*)d_in[9];
    const float* Wv    = (const float*)d_in[10];
    const float* bv    = (const float*)d_in[11];
    const float* gamma = (const float*)d_in[12];
    float* out = (float*)d_out;

    // ws layout (bf16 elts unless noted):
    // Q 4MB | K 4MB | V 16MB | Wb 768KB | biasb 4KB f32 | O_ws 33.5MB | l_ws 128KB f32
    unsigned short* Q     = (unsigned short*)d_ws;
    unsigned short* K     = Q + (size_t)B_ * N_ * D_;
    unsigned short* V     = K + (size_t)B_ * N_ * D_;
    unsigned short* Wb    = V + (size_t)B_ * C_ * N_;
    float*          biasb = (float*)(Wb + 768 * 512);
    unsigned short* O_ws  = (unsigned short*)(biasb + 1024);
    float*          l_ws  = (float*)(O_ws + (size_t)2 * B_ * C_ * N_);

    cvt_w_kernel<<<dim3(192), 256, 0, stream>>>(
        Wq, bq, Wk, bk, Wdq, bdq, Wdk, bdk, Wv, bv, Wb, biasb);
    proj_kernel<<<dim3(128, 4, 2), 256, 0, stream>>>(
        x_rgb, x_dep, Wb, biasb, Q, K, V);
    attn_kernel<<<dim3(64, 4, 2), 256, 0, stream>>>(
        Q, K, V, O_ws, l_ws);
    combine_kernel<<<dim3(8192), 256, 0, stream>>>(
        O_ws, l_ws, x_rgb, gamma, out);
}

// Round 5
// 345.197 us; speedup vs baseline: 1.1930x; 1.1930x over previous
//
#include <hip/hip_runtime.h>
#include <math.h>

#define B_ 4
#define C_ 512
#define D_ 128
#define N_ 4096

typedef short s4v __attribute__((ext_vector_type(4)));
typedef short s8v __attribute__((ext_vector_type(8)));
typedef float f4v __attribute__((ext_vector_type(4)));

__device__ __forceinline__ unsigned short f2bf(float x) {
    union { float f; unsigned u; } v; v.f = x;
    unsigned r = v.u + 0x7FFF + ((v.u >> 16) & 1);   // RNE
    return (unsigned short)(r >> 16);
}
__device__ __forceinline__ float bf2f(unsigned short h) {
    union { unsigned u; float f; } v; v.u = ((unsigned)h) << 16; return v.f;
}

// ---------------------------------------------------------------------------
// W/bias pre-convert: Wb rows [0:64]=Wq | [64:128]=Wk | [128:640]=Wv |
// [640:704]=Wdq | [704:768]=Wdk (bf16, row-major 512). biasb same order f32.
// ---------------------------------------------------------------------------
__global__ __launch_bounds__(256) void cvt_w_kernel(
    const float* __restrict__ Wq,  const float* __restrict__ bq,
    const float* __restrict__ Wk,  const float* __restrict__ bk,
    const float* __restrict__ Wdq, const float* __restrict__ bdq,
    const float* __restrict__ Wdk, const float* __restrict__ bdk,
    const float* __restrict__ Wv,  const float* __restrict__ bv,
    unsigned short* __restrict__ Wb, float* __restrict__ biasb)
{
    int t = blockIdx.x * 256 + threadIdx.x;        // 192 blocks
    int e0 = t * 8;
    int row = e0 >> 9, c = e0 & 511;
    const float* src; int r0;
    if (row < 64)       { src = Wq;  r0 = row; }
    else if (row < 128) { src = Wk;  r0 = row - 64; }
    else if (row < 640) { src = Wv;  r0 = row - 128; }
    else if (row < 704) { src = Wdq; r0 = row - 640; }
    else                { src = Wdk; r0 = row - 704; }
    const float* p = src + (size_t)r0 * 512 + c;
    s8v o;
    #pragma unroll
    for (int u = 0; u < 8; ++u) ((unsigned short*)&o)[u] = f2bf(p[u]);
    *(s8v*)&Wb[e0] = o;
    if (blockIdx.x == 0) {
        #pragma unroll
        for (int s = 0; s < 3; ++s) {
            int o2 = threadIdx.x + 256 * s;
            float v;
            if (o2 < 64)       v = bq[o2];
            else if (o2 < 128) v = bk[o2 - 64];
            else if (o2 < 640) v = bv[o2 - 128];
            else if (o2 < 704) v = bdq[o2 - 640];
            else               v = bdk[o2 - 704];
            biasb[o2] = v;
        }
    }
}

// ---------------------------------------------------------------------------
// Projection GEMM, x read ONCE. Grid (128 i-tiles of 32, 4 b, 2 streams).
// Block stages its x slice [32 i x 512 c] -> LDS bf16 (transposed), then
// loops o-chunks of 32 (rgb: 20 chunks = Wq|Wk|Wv; dep: 4 = Wdq|Wdk).
// W A-frags read directly from global bf16 (L1/L2-hot, shared by all blocks).
// LDS 33.3 KB -> 4 blocks/CU, 16 waves for latency hiding.
// ---------------------------------------------------------------------------
__global__ __launch_bounds__(256) void proj_kernel(
    const float* __restrict__ x_rgb, const float* __restrict__ x_dep,
    const unsigned short* __restrict__ Wb, const float* __restrict__ biasb,
    unsigned short* __restrict__ Q, unsigned short* __restrict__ K,
    unsigned short* __restrict__ V)
{
    __shared__ __align__(16) unsigned short Xs[32 * 520];
    const int i0 = blockIdx.x * 32;
    const int b  = blockIdx.y;
    const int st = blockIdx.z;                    // 0=rgb, 1=dep
    const int t = threadIdx.x, w = t >> 6;
    const int lane = t & 63, col = lane & 15, quad = lane >> 4;

    const float* Xb = (st ? x_dep : x_rgb) + (size_t)b * C_ * N_;

    // stage x [512 c x 32 i] -> Xs[i][c] bf16 (4x4 transpose blocks)
    #pragma unroll
    for (int s = 0; s < 4; ++s) {
        int p  = t + 256 * s;
        int ig = p & 7, cq = p >> 3;
        int i  = ig * 4, c = cq * 4;
        const float* xp = Xb + (size_t)c * N_ + i0 + i;
        float4 r0 = *(const float4*)(xp);
        float4 r1 = *(const float4*)(xp + N_);
        float4 r2 = *(const float4*)(xp + 2 * N_);
        float4 r3 = *(const float4*)(xp + 3 * N_);
        s4v p0 = { (short)f2bf(r0.x), (short)f2bf(r1.x), (short)f2bf(r2.x), (short)f2bf(r3.x) };
        s4v p1 = { (short)f2bf(r0.y), (short)f2bf(r1.y), (short)f2bf(r2.y), (short)f2bf(r3.y) };
        s4v p2 = { (short)f2bf(r0.z), (short)f2bf(r1.z), (short)f2bf(r2.z), (short)f2bf(r3.z) };
        s4v p3 = { (short)f2bf(r0.w), (short)f2bf(r1.w), (short)f2bf(r2.w), (short)f2bf(r3.w) };
        *(s4v*)&Xs[(i + 0) * 520 + c] = p0;
        *(s4v*)&Xs[(i + 1) * 520 + c] = p1;
        *(s4v*)&Xs[(i + 2) * 520 + c] = p2;
        *(s4v*)&Xs[(i + 3) * 520 + c] = p3;
    }
    __syncthreads();

    const int nmc   = st ? 4 : 20;
    const int obase = st ? 640 : 0;
    const int ot = (w & 1) * 16, it = (w >> 1) * 16;

    for (int mc = 0; mc < nmc; ++mc) {
        const int o0 = obase + mc * 32 + ot;
        const unsigned short* wp = Wb + ((size_t)(o0 + col) << 9) + quad * 8;
        const unsigned short* xp = &Xs[(it + col) * 520 + quad * 8];
        f4v acc = {0.f, 0.f, 0.f, 0.f};
        const bool isV = (st == 0) && (mc >= 4);
        if (!isV) {
            #pragma unroll 8
            for (int kk = 0; kk < 16; ++kk) {
                s8v wf = *(const s8v*)(wp + kk * 32);
                s8v xf = *(const s8v*)(xp + kk * 32);
                acc = __builtin_amdgcn_mfma_f32_16x16x32_bf16(wf, xf, acc, 0, 0, 0);
            }
            float4 bi = *(const float4*)&biasb[o0 + quad * 4];
            s4v pk = { (short)f2bf(acc[0] + bi.x), (short)f2bf(acc[1] + bi.y),
                       (short)f2bf(acc[2] + bi.z), (short)f2bf(acc[3] + bi.w) };
            unsigned short* dst; int dbase;
            if (o0 < 64)        { dst = Q; dbase = o0; }
            else if (o0 < 128)  { dst = K; dbase = o0 - 64; }
            else if (o0 < 704)  { dst = Q; dbase = 64 + (o0 - 640); }
            else                { dst = K; dbase = 64 + (o0 - 704); }
            *(s4v*)&dst[((size_t)b * N_ + i0 + it + col) * D_ + dbase + quad * 4] = pk;
        } else {
            #pragma unroll 8
            for (int kk = 0; kk < 16; ++kk) {
                s8v wf = *(const s8v*)(wp + kk * 32);
                s8v xf = *(const s8v*)(xp + kk * 32);
                acc = __builtin_amdgcn_mfma_f32_16x16x32_bf16(xf, wf, acc, 0, 0, 0);
            }
            float bi = biasb[o0 + col];
            s4v pk = { (short)f2bf(acc[0] + bi), (short)f2bf(acc[1] + bi),
                       (short)f2bf(acc[2] + bi), (short)f2bf(acc[3] + bi) };
            int c = o0 - 128 + col;
            *(s4v*)&V[((size_t)b * C_ + c) * N_ + i0 + it + quad * 4] = pk;
        }
    }
}

// ---------------------------------------------------------------------------
// MFMA flash attention, j-split 2-way, unnormalized softmax (partials exactly
// additive; |S|<~14 so exp/l fit fp32 comfortably).
// Grid (64 i-tiles, 4 b, 2 j-halves) = 512 blocks; __launch_bounds__(256,2)
// caps total regs at 256 (128 AGPR acc + ~100 arch) -> 2 blocks/CU resident
// (LDS 55KB x2 = 110KB). Transient staging regs (issued at loop top, dead
// after commit) replace R4's persistent prefetch to fit the budget.
// O partials stored in native register layout (no LDS transpose):
//   O_ws[(((jh*4+b)*64+i0b)*4+w)*8192 + (ct*4+rt)*256 + lane*4 + r]
//   where i = i0b*64 + rt*16 + quad*4 + r, c = w*128 + ct*16 + col.
// ---------------------------------------------------------------------------
__global__ __launch_bounds__(256, 2) void attn_kernel(
    const unsigned short* __restrict__ Q, const unsigned short* __restrict__ K,
    const unsigned short* __restrict__ V,
    unsigned short* __restrict__ O_ws, float* __restrict__ l_ws)
{
    __shared__ __align__(16) unsigned short Ks[32 * 136];
    __shared__ __align__(16) unsigned short Ps[64 * 40];
    __shared__ __align__(16) unsigned short Vs[512 * 40];
    __shared__ float lred[2][64];

    const int b  = blockIdx.y;
    const int i0 = blockIdx.x * 64;
    const int jh = blockIdx.z;
    const int jb = jh * 2048;
    const int t = threadIdx.x, w = t >> 6;
    const int lane = t & 63, col = lane & 15, quad = lane >> 4;
    const int ih = w & 1, jq = w >> 1;

    const unsigned short* Kg = K + (size_t)b * N_ * D_;
    const unsigned short* Vg = V + (size_t)b * C_ * N_;

    // Q B-frags for this wave's 2 i-16 groups (rows ih*32 + ig*16 + col)
    s8v qf[2][4];
    #pragma unroll
    for (int ig = 0; ig < 2; ++ig) {
        const unsigned short* qr =
            Q + ((size_t)b * N_ + i0 + ih * 32 + ig * 16 + col) * D_ + quad * 8;
        #pragma unroll
        for (int kk = 0; kk < 4; ++kk) qf[ig][kk] = *(const s8v*)(qr + kk * 32);
    }

    f4v accO[4][8];
    #pragma unroll
    for (int rt = 0; rt < 4; ++rt)
        #pragma unroll
        for (int ct = 0; ct < 8; ++ct) accO[rt][ct] = (f4v){0.f, 0.f, 0.f, 0.f};
    float lsum[2] = {0.f, 0.f};

    for (int tt = 0; tt < 64; ++tt) {
        const int j0 = jb + tt * 32;
        // ---- issue staging loads (regs transient; in flight across B1) ----
        s8v kt[2], vt[8];
        #pragma unroll
        for (int s = 0; s < 2; ++s) {
            int gi = t + 256 * s;
            kt[s] = *(const s8v*)&Kg[(size_t)(j0 + (gi >> 4)) * D_ + (gi & 15) * 8];
        }
        #pragma unroll
        for (int s = 0; s < 8; ++s) {
            int gi = t + 256 * s;
            vt[s] = *(const s8v*)&Vg[(size_t)(gi >> 2) * N_ + j0 + (gi & 3) * 8];
        }
        __syncthreads();                     // B1: prior iter's LDS reads done
        #pragma unroll
        for (int s = 0; s < 2; ++s) {
            int gi = t + 256 * s;
            *(s8v*)&Ks[(gi >> 4) * 136 + (gi & 15) * 8] = kt[s];
        }
        #pragma unroll
        for (int s = 0; s < 8; ++s) {
            int gi = t + 256 * s;
            *(s8v*)&Vs[(gi >> 2) * 40 + (gi & 3) * 8] = vt[s];
        }
        __syncthreads();                     // B2: tile staged
        // ---- S^T = K Q^T for this wave's (ih, jq): 2 i-tiles ----
        f4v s0 = (f4v){0.f, 0.f, 0.f, 0.f};
        f4v s1 = (f4v){0.f, 0.f, 0.f, 0.f};
        #pragma unroll
        for (int kk = 0; kk < 4; ++kk) {
            s8v kf = *(const s8v*)&Ks[(jq * 16 + col) * 136 + kk * 32 + quad * 8];
            s0 = __builtin_amdgcn_mfma_f32_16x16x32_bf16(kf, qf[0][kk], s0, 0, 0, 0);
            s1 = __builtin_amdgcn_mfma_f32_16x16x32_bf16(kf, qf[1][kk], s1, 0, 0, 0);
        }
        // ---- P = exp(S): lane holds i=col, j = jq*16 + quad*4 + r ----
        #pragma unroll
        for (int ig = 0; ig < 2; ++ig) {
            f4v sv = ig ? s1 : s0;
            s4v p; float ls = 0.f;
            #pragma unroll
            for (int r = 0; r < 4; ++r) {
                float e = __expf(sv[r]);
                ls += e;
                p[r] = (short)f2bf(e);
            }
            lsum[ig] += ls;
            *(s4v*)&Ps[(ih * 32 + ig * 16 + col) * 40 + jq * 16 + quad * 4] = p;
        }
        __syncthreads();                     // B3: P visible to all waves
        // ---- O += P V : wave w owns c in [w*128, w*128+128) ----
        s8v pf[4];
        #pragma unroll
        for (int rt = 0; rt < 4; ++rt)
            pf[rt] = *(const s8v*)&Ps[(rt * 16 + col) * 40 + quad * 8];
        #pragma unroll
        for (int ct = 0; ct < 8; ++ct) {
            s8v vf = *(const s8v*)&Vs[(w * 128 + ct * 16 + col) * 40 + quad * 8];
            #pragma unroll
            for (int rt = 0; rt < 4; ++rt)
                accO[rt][ct] = __builtin_amdgcn_mfma_f32_16x16x32_bf16(pf[rt], vf, accO[rt][ct], 0, 0, 0);
        }
    }

    // ---- partial l: reduce over quads, combine jq halves via LDS ----
    #pragma unroll
    for (int ig = 0; ig < 2; ++ig) {
        float v = lsum[ig];
        v += __shfl_xor(v, 16);
        v += __shfl_xor(v, 32);
        if (quad == 0) lred[jq][ih * 32 + ig * 16 + col] = v;
    }
    __syncthreads();
    if (t < 64)
        l_ws[((size_t)jh * B_ + b) * N_ + i0 + t] = lred[0][t] + lred[1][t];

    // ---- O partial store in native register layout (coalesced 8B/lane) ----
    const size_t wbase =
        ((((size_t)jh * B_ + b) * 64 + blockIdx.x) * 4 + w) * 8192;
    #pragma unroll
    for (int ct = 0; ct < 8; ++ct)
        #pragma unroll
        for (int rt = 0; rt < 4; ++rt) {
            s4v pk = { (short)f2bf(accO[rt][ct][0]), (short)f2bf(accO[rt][ct][1]),
                       (short)f2bf(accO[rt][ct][2]), (short)f2bf(accO[rt][ct][3]) };
            *(s4v*)&O_ws[wbase + (size_t)(ct * 4 + rt) * 256 + lane * 4] = pk;
        }
}

// ---------------------------------------------------------------------------
// Combine: out = gamma * (O0+O1)/(l0+l1) + x_rgb. Inverts the native
// register layout: 4 consecutive i == the 4 regs of one s4v.
// ---------------------------------------------------------------------------
__global__ __launch_bounds__(256) void combine_kernel(
    const unsigned short* __restrict__ O_ws, const float* __restrict__ l_ws,
    const float* __restrict__ x_rgb, const float* __restrict__ gamma,
    float* __restrict__ out)
{
    const size_t half = (size_t)B_ * 64 * 4 * 8192;   // elems per j-half
    int idx = blockIdx.x * 256 + threadIdx.x;         // 8192 blocks
    int i4 = idx & 1023;
    int c  = (idx >> 10) & 511;
    int b  = idx >> 19;
    int i  = i4 * 4;
    int i0b = i >> 6, il = i & 63;
    int rt = il >> 4, qd = (il >> 2) & 3;
    int w = c >> 7, cl = c & 127, ct = cl >> 4, col = cl & 15;
    size_t obase = (((size_t)b * 64 + i0b) * 4 + w) * 8192
                 + (size_t)(ct * 4 + rt) * 256 + (qd * 16 + col) * 4;
    s4v o0 = *(const s4v*)&O_ws[obase];
    s4v o1 = *(const s4v*)&O_ws[half + obase];
    float4 l0 = *(const float4*)&l_ws[(size_t)b * N_ + i];
    float4 l1 = *(const float4*)&l_ws[(size_t)(B_ + b) * N_ + i];
    size_t base = ((size_t)b * C_ + c) * N_ + i;
    float4 x4 = *(const float4*)&x_rgb[base];
    float g = gamma[0];
    float4 r;
    r.x = g * (bf2f((unsigned short)o0[0]) + bf2f((unsigned short)o1[0])) / (l0.x + l1.x) + x4.x;
    r.y = g * (bf2f((unsigned short)o0[1]) + bf2f((unsigned short)o1[1])) / (l0.y + l1.y) + x4.y;
    r.z = g * (bf2f((unsigned short)o0[2]) + bf2f((unsigned short)o1[2])) / (l0.z + l1.z) + x4.z;
    r.w = g * (bf2f((unsigned short)o0[3]) + bf2f((unsigned short)o1[3])) / (l0.w + l1.w) + x4.w;
    *(float4*)&out[base] = r;
}

// ---------------------------------------------------------------------------
extern "C" void kernel_launch(void* const* d_in, const int* in_sizes, int n_in,
                              void* d_out, int out_size, void* d_ws, size_t ws_size,
                              hipStream_t stream) {
    (void)in_sizes; (void)n_in; (void)out_size; (void)ws_size;
    const float* x_rgb = (const float*)d_in[0];
    const float* x_dep = (const float*)d_in[1];
    const float* Wq    = (const float*)d_in[2];
    const float* bq    = (const float*)d_in[3];
    const float* Wk    = (const float*)d_in[4];
    const float* bk    = (const float*)d_in[5];
    const float* Wdq   = (const float*)d_in[6];
    const float* bdq   = (const float*)d_in[7];
    const float* Wdk   = (const float*)d_in[8];
    const float* bdk   = (const float*)d_in[9];
    const float* Wv    = (const float*)d_in[10];
    const float* bv    = (const float*)d_in[11];
    const float* gamma = (const float*)d_in[12];
    float* out = (float*)d_out;

    // ws layout (bf16 elts unless noted):
    // Q 4MB | K 4MB | V 16MB | Wb 768KB | biasb 4KB f32 | O_ws 33.5MB | l_ws 128KB f32
    unsigned short* Q     = (unsigned short*)d_ws;
    unsigned short* K     = Q + (size_t)B_ * N_ * D_;
    unsigned short* V     = K + (size_t)B_ * N_ * D_;
    unsigned short* Wb    = V + (size_t)B_ * C_ * N_;
    float*          biasb = (float*)(Wb + 768 * 512);
    unsigned short* O_ws  = (unsigned short*)(biasb + 1024);
    float*          l_ws  = (float*)(O_ws + (size_t)2 * B_ * C_ * N_);

    cvt_w_kernel<<<dim3(192), 256, 0, stream>>>(
        Wq, bq, Wk, bk, Wdq, bdq, Wdk, bdk, Wv, bv, Wb, biasb);
    proj_kernel<<<dim3(128, 4, 2), 256, 0, stream>>>(
        x_rgb, x_dep, Wb, biasb, Q, K, V);
    attn_kernel<<<dim3(64, 4, 2), 256, 0, stream>>>(
        Q, K, V, O_ws, l_ws);
    combine_kernel<<<dim3(8192), 256, 0, stream>>>(
        O_ws, l_ws, x_rgb, gamma, out);
}

// Round 6
// 297.868 us; speedup vs baseline: 1.3826x; 1.1589x over previous
//
#include <hip/hip_runtime.h>
#include <math.h>

#define B_ 4
#define C_ 512
#define D_ 128
#define N_ 4096

typedef short s4v __attribute__((ext_vector_type(4)));
typedef short s8v __attribute__((ext_vector_type(8)));
typedef float f4v __attribute__((ext_vector_type(4)));

__device__ __forceinline__ unsigned short f2bf(float x) {
    union { float f; unsigned u; } v; v.f = x;
    unsigned r = v.u + 0x7FFF + ((v.u >> 16) & 1);   // RNE
    return (unsigned short)(r >> 16);
}
__device__ __forceinline__ float bf2f(unsigned short h) {
    union { unsigned u; float f; } v; v.u = ((unsigned)h) << 16; return v.f;
}

// ---------------------------------------------------------------------------
// W/bias pre-convert: Wb rows [0:64]=Wq | [64:128]=Wk | [128:640]=Wv |
// [640:704]=Wdq | [704:768]=Wdk (bf16, row-major 512). biasb same order f32.
// ---------------------------------------------------------------------------
__global__ __launch_bounds__(256) void cvt_w_kernel(
    const float* __restrict__ Wq,  const float* __restrict__ bq,
    const float* __restrict__ Wk,  const float* __restrict__ bk,
    const float* __restrict__ Wdq, const float* __restrict__ bdq,
    const float* __restrict__ Wdk, const float* __restrict__ bdk,
    const float* __restrict__ Wv,  const float* __restrict__ bv,
    unsigned short* __restrict__ Wb, float* __restrict__ biasb)
{
    int t = blockIdx.x * 256 + threadIdx.x;        // 192 blocks
    int e0 = t * 8;
    int row = e0 >> 9, c = e0 & 511;
    const float* src; int r0;
    if (row < 64)       { src = Wq;  r0 = row; }
    else if (row < 128) { src = Wk;  r0 = row - 64; }
    else if (row < 640) { src = Wv;  r0 = row - 128; }
    else if (row < 704) { src = Wdq; r0 = row - 640; }
    else                { src = Wdk; r0 = row - 704; }
    const float* p = src + (size_t)r0 * 512 + c;
    s8v o;
    #pragma unroll
    for (int u = 0; u < 8; ++u) ((unsigned short*)&o)[u] = f2bf(p[u]);
    *(s8v*)&Wb[e0] = o;
    if (blockIdx.x == 0) {
        #pragma unroll
        for (int s = 0; s < 3; ++s) {
            int o2 = threadIdx.x + 256 * s;
            float v;
            if (o2 < 64)       v = bq[o2];
            else if (o2 < 128) v = bk[o2 - 64];
            else if (o2 < 640) v = bv[o2 - 128];
            else if (o2 < 704) v = bdq[o2 - 640];
            else               v = bdk[o2 - 704];
            biasb[o2] = v;
        }
    }
}

// ---------------------------------------------------------------------------
// Transpose-convert: x[st][b][c][i] fp32 -> Xt[st][b][i][c] bf16.
// Grid (64 iT x 8 cT, 4 b, 2 st) = 4096 blocks; 64x64 tile via LDS
// (stride 72 shorts: b64 writes 2-way, b128 reads conflict-free).
// Memory-bound: 67 MB read + 33.5 MB write.
// ---------------------------------------------------------------------------
__global__ __launch_bounds__(256) void xpose_kernel(
    const float* __restrict__ x_rgb, const float* __restrict__ x_dep,
    unsigned short* __restrict__ Xt)
{
    __shared__ __align__(16) unsigned short Ls[64 * 72];
    const int cT = blockIdx.x & 7, iT = blockIdx.x >> 3;
    const int b = blockIdx.y, st = blockIdx.z;
    const int t = threadIdx.x;
    const float* Xb = (st ? x_dep : x_rgb) + (size_t)b * C_ * N_;

    const int c4 = t >> 4, i4 = t & 15;          // 4c x 4i block per thread
    {
        const float* xp = Xb + (size_t)(cT * 64 + c4 * 4) * N_ + iT * 64 + i4 * 4;
        float4 r0 = *(const float4*)(xp);
        float4 r1 = *(const float4*)(xp + N_);
        float4 r2 = *(const float4*)(xp + 2 * N_);
        float4 r3 = *(const float4*)(xp + 3 * N_);
        s4v p0 = { (short)f2bf(r0.x), (short)f2bf(r1.x), (short)f2bf(r2.x), (short)f2bf(r3.x) };
        s4v p1 = { (short)f2bf(r0.y), (short)f2bf(r1.y), (short)f2bf(r2.y), (short)f2bf(r3.y) };
        s4v p2 = { (short)f2bf(r0.z), (short)f2bf(r1.z), (short)f2bf(r2.z), (short)f2bf(r3.z) };
        s4v p3 = { (short)f2bf(r0.w), (short)f2bf(r1.w), (short)f2bf(r2.w), (short)f2bf(r3.w) };
        *(s4v*)&Ls[(i4 * 4 + 0) * 72 + c4 * 4] = p0;
        *(s4v*)&Ls[(i4 * 4 + 1) * 72 + c4 * 4] = p1;
        *(s4v*)&Ls[(i4 * 4 + 2) * 72 + c4 * 4] = p2;
        *(s4v*)&Ls[(i4 * 4 + 3) * 72 + c4 * 4] = p3;
    }
    __syncthreads();
    unsigned short* dst = Xt + ((size_t)(st * 4 + b) * N_ + iT * 64) * 512 + cT * 64;
    #pragma unroll
    for (int s = 0; s < 2; ++s) {
        int lin = t + 256 * s;
        int row = lin >> 3, g = lin & 7;
        *(s8v*)&dst[(size_t)row * 512 + g * 8] = *(const s8v*)&Ls[row * 72 + g * 8];
    }
}

// ---------------------------------------------------------------------------
// Projection GEMM (m97-style): out[768 m x 16384 n] = Wb @ Xt^T, K=512.
// Grid (128 n-tiles, 6 m-tiles): by 0..4 = rgb rows (Wq|Wk|Wv), by 5 = dep
// (Wdq|Wdk). 128x128 tile, BK=64, wave = 64x64 quadrant (4x4 C-frags,
// 64 AGPR). LDS unpadded stride-64 with XOR granule swizzle g^(row&7):
// conflict-free b128 on both staging writes and frag reads. 3 blocks/CU.
// Epilogue routes rows: Q/K -> [b,i,d] s4v stores; V -> [b,c,j] b16 stores.
// ---------------------------------------------------------------------------
__global__ __launch_bounds__(256) void gemm_kernel(
    const unsigned short* __restrict__ Wb, const float* __restrict__ biasb,
    const unsigned short* __restrict__ Xt,
    unsigned short* __restrict__ Q, unsigned short* __restrict__ K,
    unsigned short* __restrict__ V)
{
    __shared__ __align__(16) unsigned short Ws[128 * 64];
    __shared__ __align__(16) unsigned short Xs[128 * 64];
    const int b  = blockIdx.x >> 5;
    const int i0 = (blockIdx.x & 31) * 128;
    const int by = blockIdx.y;
    const int mbase = by * 128;
    const int st = (by == 5);
    const int t = threadIdx.x, w = t >> 6;
    const int lane = t & 63, col = lane & 15, quad = lane >> 4;
    const int mh = (w & 1) * 64, nh = (w >> 1) * 64;

    const unsigned short* Wg = Wb + (size_t)mbase * 512;
    const unsigned short* Xg = Xt + ((size_t)(st * 4 + b) * N_ + i0) * 512;

    f4v acc[4][4];
    #pragma unroll
    for (int mt = 0; mt < 4; ++mt)
        #pragma unroll
        for (int nt = 0; nt < 4; ++nt) acc[mt][nt] = (f4v){0.f, 0.f, 0.f, 0.f};

    for (int kc = 0; kc < 8; ++kc) {
        const int k0 = kc * 64;
        s8v wt[4], xt[4];
        #pragma unroll
        for (int s = 0; s < 4; ++s) {
            int lin = t + 256 * s;
            int row = lin >> 3, g = lin & 7;
            wt[s] = *(const s8v*)&Wg[(size_t)row * 512 + k0 + g * 8];
            xt[s] = *(const s8v*)&Xg[(size_t)row * 512 + k0 + g * 8];
        }
        __syncthreads();                       // prior iter's frag reads done
        #pragma unroll
        for (int s = 0; s < 4; ++s) {
            int lin = t + 256 * s;
            int row = lin >> 3, g = lin & 7;
            int soff = row * 64 + ((g ^ (row & 7)) * 8);
            *(s8v*)&Ws[soff] = wt[s];
            *(s8v*)&Xs[soff] = xt[s];
        }
        __syncthreads();                       // tile staged
        #pragma unroll
        for (int kk = 0; kk < 2; ++kk) {
            const int gq = kk * 4 + quad;
            s8v af[4], bf[4];
            #pragma unroll
            for (int mt = 0; mt < 4; ++mt) {
                int r = mh + mt * 16 + col;
                af[mt] = *(const s8v*)&Ws[r * 64 + ((gq ^ (r & 7)) * 8)];
            }
            #pragma unroll
            for (int nt = 0; nt < 4; ++nt) {
                int r = nh + nt * 16 + col;
                bf[nt] = *(const s8v*)&Xs[r * 64 + ((gq ^ (r & 7)) * 8)];
            }
            #pragma unroll
            for (int nt = 0; nt < 4; ++nt)
                #pragma unroll
                for (int mt = 0; mt < 4; ++mt)
                    acc[mt][nt] = __builtin_amdgcn_mfma_f32_16x16x32_bf16(
                        af[mt], bf[nt], acc[mt][nt], 0, 0, 0);
        }
    }

    // ---- epilogue ----
    const int mlo0 = mbase + mh;               // wave-uniform
    #pragma unroll
    for (int mt = 0; mt < 4; ++mt) {
        const int mlo = mlo0 + mt * 16;
        f4v bi = *(const f4v*)&biasb[mlo + quad * 4];
        if (mlo < 128 || mlo >= 640) {         // Q/K rows
            unsigned short* dst; int dbase;
            if (mlo < 64)       { dst = Q; dbase = mlo; }
            else if (mlo < 128) { dst = K; dbase = mlo - 64; }
            else if (mlo < 704) { dst = Q; dbase = 64 + (mlo - 640); }
            else                { dst = K; dbase = 64 + (mlo - 704); }
            #pragma unroll
            for (int nt = 0; nt < 4; ++nt) {
                int i = i0 + nh + nt * 16 + col;
                s4v pk = { (short)f2bf(acc[mt][nt][0] + bi[0]),
                           (short)f2bf(acc[mt][nt][1] + bi[1]),
                           (short)f2bf(acc[mt][nt][2] + bi[2]),
                           (short)f2bf(acc[mt][nt][3] + bi[3]) };
                *(s4v*)&dst[((size_t)b * N_ + i) * D_ + dbase + quad * 4] = pk;
            }
        } else {                               // V rows
            int c0 = mlo - 128 + quad * 4;
            #pragma unroll
            for (int nt = 0; nt < 4; ++nt) {
                int i = i0 + nh + nt * 16 + col;
                #pragma unroll
                for (int r = 0; r < 4; ++r)
                    V[((size_t)b * C_ + c0 + r) * N_ + i] =
                        f2bf(acc[mt][nt][r] + bi[r]);
            }
        }
    }
}

// ---------------------------------------------------------------------------
// MFMA flash attention, j-split 2-way, unnormalized softmax (partials exactly
// additive; |S|<~14). Grid (64,4,2); __launch_bounds__(256,2) -> 2 blocks/CU.
// Vs: UNPADDED stride 32 + granule swizzle s=(g+c+(c>>2))&3 — conflict-free
// b128 on staging writes and vf reads (replaces R5's stride-40 2-3-way).
// LDS: Ks[32][136] 8704 | Ps[64][40] 5120 | Vs[512][32] 32768 | lred 512.
// ---------------------------------------------------------------------------
__global__ __launch_bounds__(256, 2) void attn_kernel(
    const unsigned short* __restrict__ Q, const unsigned short* __restrict__ K,
    const unsigned short* __restrict__ V,
    unsigned short* __restrict__ O_ws, float* __restrict__ l_ws)
{
    __shared__ __align__(16) unsigned short Ks[32 * 136];
    __shared__ __align__(16) unsigned short Ps[64 * 40];
    __shared__ __align__(16) unsigned short Vs[512 * 32];
    __shared__ float lred[2][64];

    const int b  = blockIdx.y;
    const int i0 = blockIdx.x * 64;
    const int jh = blockIdx.z;
    const int jb = jh * 2048;
    const int t = threadIdx.x, w = t >> 6;
    const int lane = t & 63, col = lane & 15, quad = lane >> 4;
    const int ih = w & 1, jq = w >> 1;

    const unsigned short* Kg = K + (size_t)b * N_ * D_;
    const unsigned short* Vg = V + (size_t)b * C_ * N_;

    s8v qf[2][4];
    #pragma unroll
    for (int ig = 0; ig < 2; ++ig) {
        const unsigned short* qr =
            Q + ((size_t)b * N_ + i0 + ih * 32 + ig * 16 + col) * D_ + quad * 8;
        #pragma unroll
        for (int kk = 0; kk < 4; ++kk) qf[ig][kk] = *(const s8v*)(qr + kk * 32);
    }

    f4v accO[4][8];
    #pragma unroll
    for (int rt = 0; rt < 4; ++rt)
        #pragma unroll
        for (int ct = 0; ct < 8; ++ct) accO[rt][ct] = (f4v){0.f, 0.f, 0.f, 0.f};
    float lsum[2] = {0.f, 0.f};

    for (int tt = 0; tt < 64; ++tt) {
        const int j0 = jb + tt * 32;
        s8v kt[2], vt[8];
        #pragma unroll
        for (int s = 0; s < 2; ++s) {
            int gi = t + 256 * s;
            kt[s] = *(const s8v*)&Kg[(size_t)(j0 + (gi >> 4)) * D_ + (gi & 15) * 8];
        }
        #pragma unroll
        for (int s = 0; s < 8; ++s) {
            int gi = t + 256 * s;
            vt[s] = *(const s8v*)&Vg[(size_t)(gi >> 2) * N_ + j0 + (gi & 3) * 8];
        }
        __syncthreads();                     // B1: prior iter's LDS reads done
        #pragma unroll
        for (int s = 0; s < 2; ++s) {
            int gi = t + 256 * s;
            *(s8v*)&Ks[(gi >> 4) * 136 + (gi & 15) * 8] = kt[s];
        }
        #pragma unroll
        for (int s = 0; s < 8; ++s) {
            int gi = t + 256 * s;
            int c = gi >> 2, g = gi & 3;
            int sw = (g + c + (c >> 2)) & 3;
            *(s8v*)&Vs[c * 32 + sw * 8] = vt[s];
        }
        __syncthreads();                     // B2: tile staged
        f4v s0 = (f4v){0.f, 0.f, 0.f, 0.f};
        f4v s1 = (f4v){0.f, 0.f, 0.f, 0.f};
        #pragma unroll
        for (int kk = 0; kk < 4; ++kk) {
            s8v kf = *(const s8v*)&Ks[(jq * 16 + col) * 136 + kk * 32 + quad * 8];
            s0 = __builtin_amdgcn_mfma_f32_16x16x32_bf16(kf, qf[0][kk], s0, 0, 0, 0);
            s1 = __builtin_amdgcn_mfma_f32_16x16x32_bf16(kf, qf[1][kk], s1, 0, 0, 0);
        }
        #pragma unroll
        for (int ig = 0; ig < 2; ++ig) {
            f4v sv = ig ? s1 : s0;
            s4v p; float ls = 0.f;
            #pragma unroll
            for (int r = 0; r < 4; ++r) {
                float e = __expf(sv[r]);
                ls += e;
                p[r] = (short)f2bf(e);
            }
            lsum[ig] += ls;
            *(s4v*)&Ps[(ih * 32 + ig * 16 + col) * 40 + jq * 16 + quad * 4] = p;
        }
        __syncthreads();                     // B3: P visible
        s8v pf[4];
        #pragma unroll
        for (int rt = 0; rt < 4; ++rt)
            pf[rt] = *(const s8v*)&Ps[(rt * 16 + col) * 40 + quad * 8];
        #pragma unroll
        for (int ct = 0; ct < 8; ++ct) {
            int row = w * 128 + ct * 16 + col;
            int sw = (quad + row + (row >> 2)) & 3;
            s8v vf = *(const s8v*)&Vs[row * 32 + sw * 8];
            #pragma unroll
            for (int rt = 0; rt < 4; ++rt)
                accO[rt][ct] = __builtin_amdgcn_mfma_f32_16x16x32_bf16(pf[rt], vf, accO[rt][ct], 0, 0, 0);
        }
    }

    #pragma unroll
    for (int ig = 0; ig < 2; ++ig) {
        float v = lsum[ig];
        v += __shfl_xor(v, 16);
        v += __shfl_xor(v, 32);
        if (quad == 0) lred[jq][ih * 32 + ig * 16 + col] = v;
    }
    __syncthreads();
    if (t < 64)
        l_ws[((size_t)jh * B_ + b) * N_ + i0 + t] = lred[0][t] + lred[1][t];

    const size_t wbase =
        ((((size_t)jh * B_ + b) * 64 + blockIdx.x) * 4 + w) * 8192;
    #pragma unroll
    for (int ct = 0; ct < 8; ++ct)
        #pragma unroll
        for (int rt = 0; rt < 4; ++rt) {
            s4v pk = { (short)f2bf(accO[rt][ct][0]), (short)f2bf(accO[rt][ct][1]),
                       (short)f2bf(accO[rt][ct][2]), (short)f2bf(accO[rt][ct][3]) };
            *(s4v*)&O_ws[wbase + (size_t)(ct * 4 + rt) * 256 + lane * 4] = pk;
        }
}

// ---------------------------------------------------------------------------
// Combine: out = gamma * (O0+O1)/(l0+l1) + x_rgb (inverts native O layout).
// ---------------------------------------------------------------------------
__global__ __launch_bounds__(256) void combine_kernel(
    const unsigned short* __restrict__ O_ws, const float* __restrict__ l_ws,
    const float* __restrict__ x_rgb, const float* __restrict__ gamma,
    float* __restrict__ out)
{
    const size_t half = (size_t)B_ * 64 * 4 * 8192;   // elems per j-half
    int idx = blockIdx.x * 256 + threadIdx.x;         // 8192 blocks
    int i4 = idx & 1023;
    int c  = (idx >> 10) & 511;
    int b  = idx >> 19;
    int i  = i4 * 4;
    int i0b = i >> 6, il = i & 63;
    int rt = il >> 4, qd = (il >> 2) & 3;
    int w = c >> 7, cl = c & 127, ct = cl >> 4, col = cl & 15;
    size_t obase = (((size_t)b * 64 + i0b) * 4 + w) * 8192
                 + (size_t)(ct * 4 + rt) * 256 + (qd * 16 + col) * 4;
    s4v o0 = *(const s4v*)&O_ws[obase];
    s4v o1 = *(const s4v*)&O_ws[half + obase];
    float4 l0 = *(const float4*)&l_ws[(size_t)b * N_ + i];
    float4 l1 = *(const float4*)&l_ws[(size_t)(B_ + b) * N_ + i];
    size_t base = ((size_t)b * C_ + c) * N_ + i;
    float4 x4 = *(const float4*)&x_rgb[base];
    float g = gamma[0];
    float4 r;
    r.x = g * (bf2f((unsigned short)o0[0]) + bf2f((unsigned short)o1[0])) / (l0.x + l1.x) + x4.x;
    r.y = g * (bf2f((unsigned short)o0[1]) + bf2f((unsigned short)o1[1])) / (l0.y + l1.y) + x4.y;
    r.z = g * (bf2f((unsigned short)o0[2]) + bf2f((unsigned short)o1[2])) / (l0.z + l1.z) + x4.z;
    r.w = g * (bf2f((unsigned short)o0[3]) + bf2f((unsigned short)o1[3])) / (l0.w + l1.w) + x4.w;
    *(float4*)&out[base] = r;
}

// ---------------------------------------------------------------------------
extern "C" void kernel_launch(void* const* d_in, const int* in_sizes, int n_in,
                              void* d_out, int out_size, void* d_ws, size_t ws_size,
                              hipStream_t stream) {
    (void)in_sizes; (void)n_in; (void)out_size; (void)ws_size;
    const float* x_rgb = (const float*)d_in[0];
    const float* x_dep = (const float*)d_in[1];
    const float* Wq    = (const float*)d_in[2];
    const float* bq    = (const float*)d_in[3];
    const float* Wk    = (const float*)d_in[4];
    const float* bk    = (const float*)d_in[5];
    const float* Wdq   = (const float*)d_in[6];
    const float* bdq   = (const float*)d_in[7];
    const float* Wdk   = (const float*)d_in[8];
    const float* bdk   = (const float*)d_in[9];
    const float* Wv    = (const float*)d_in[10];
    const float* bv    = (const float*)d_in[11];
    const float* gamma = (const float*)d_in[12];
    float* out = (float*)d_out;

    // ws (bf16 elts unless noted): Q 4MB | K 4MB | V 16.8MB | Wb 768KB |
    // biasb 4KB f32 | XtO 33.5MB (Xt during proj, O_ws during attn — they
    // don't overlap in time) | l_ws 128KB f32.  Total ~59 MB.
    unsigned short* Q     = (unsigned short*)d_ws;
    unsigned short* K     = Q + (size_t)B_ * N_ * D_;
    unsigned short* V     = K + (size_t)B_ * N_ * D_;
    unsigned short* Wb    = V + (size_t)B_ * C_ * N_;
    float*          biasb = (float*)(Wb + 768 * 512);
    unsigned short* XtO   = (unsigned short*)(biasb + 1024);
    float*          l_ws  = (float*)(XtO + (size_t)2 * B_ * C_ * N_);

    cvt_w_kernel<<<dim3(192), 256, 0, stream>>>(
        Wq, bq, Wk, bk, Wdq, bdq, Wdk, bdk, Wv, bv, Wb, biasb);
    xpose_kernel<<<dim3(512, 4, 2), 256, 0, stream>>>(x_rgb, x_dep, XtO);
    gemm_kernel<<<dim3(128, 6), 256, 0, stream>>>(Wb, biasb, XtO, Q, K, V);
    attn_kernel<<<dim3(64, 4, 2), 256, 0, stream>>>(Q, K, V, XtO, l_ws);
    combine_kernel<<<dim3(8192), 256, 0, stream>>>(XtO, l_ws, x_rgb, gamma, out);
}